// Round 2
// baseline (64.296 us; speedup 1.0000x reference)
//
#include <hip/hip_runtime.h>

// Problem constants (B=64, N=600, C=256)
#define B_DIM 64
#define N_NODES 600
#define C_DIM 256
#define NV4 (N_NODES / 4)          // 150 float4 per A row
#define XROWS (B_DIM * N_NODES)    // 38400
#define XBLOCKS (XROWS / 4)        // 9600 (4 rows per 256-thr block)
#define A_ROWTILE 16
#define ABLK_PER_B ((N_NODES + A_ROWTILE - 1) / A_ROWTILE)  // 38
#define ABLOCKS (B_DIM * ABLK_PER_B)                        // 2432

constexpr float kThr = 0.003f;   // THRESHOLD
constexpr float kEps = 1e-7f;    // EPS

// ---------------------------------------------------------------------------
// K1: one block per batch. Fused: scores -> exp*mask -> sum -> alpha ->
// threshold -> stable compaction scan -> idx, K, mask_out, alpha.
// 1024 threads = 16 waves; wave w handles rows w, w+16, ...
// Sum reduction kept IDENTICAL (1024-wide LDS tree) to the passing round-0
// version so threshold-boundary numerics don't shift.
// ---------------------------------------------------------------------------
__global__ __launch_bounds__(1024)
void k_score_compact(const float* __restrict__ x,
                     const float* __restrict__ W,
                     const int* __restrict__ mask,
                     float* __restrict__ alpha,     // ws: (B,N)
                     int* __restrict__ idx,         // ws: (B,N)
                     int* __restrict__ Kbuf,        // ws: (B)
                     float* __restrict__ mask_out) {
  const int b    = blockIdx.x;
  const int t    = threadIdx.x;
  const int wave = t >> 6;
  const int lane = t & 63;

  __shared__ float sAP[N_NODES];
  __shared__ float fs[1024];
  __shared__ int   wtot[16];

  const float4 wv = reinterpret_cast<const float4*>(W)[lane];
  const float* xb = x + (size_t)b * N_NODES * C_DIM;

  // scores: one wave per row, strided by 16 waves
  for (int r = wave; r < N_NODES; r += 16) {
    const float4 xv =
        reinterpret_cast<const float4*>(xb + (size_t)r * C_DIM)[lane];
    float s = xv.x * wv.x + xv.y * wv.y + xv.z * wv.z + xv.w * wv.w;
    #pragma unroll
    for (int off = 32; off > 0; off >>= 1) s += __shfl_down(s, off, 64);
    if (lane == 0)
      sAP[r] = (mask[b * N_NODES + r] != 0) ? expf(s) : 0.0f;
  }
  __syncthreads();

  // balanced tree sum (identical order to round-0 passing kernel)
  const float ap = (t < N_NODES) ? sAP[t] : 0.0f;
  fs[t] = ap;
  __syncthreads();
  #pragma unroll
  for (int off = 512; off > 0; off >>= 1) {
    if (t < off) fs[t] += fs[t + off];
    __syncthreads();
  }
  const float S = fs[0];

  const float a = ap / (S + kEps);
  // mask==0 => ap==0 => a==0 => not kept, so (a > thr) alone is sufficient
  const int keep = (t < N_NODES && a > kThr) ? 1 : 0;

  // wave-level inclusive scan of keep (no barriers inside)
  int incl = keep;
  #pragma unroll
  for (int off = 1; off < 64; off <<= 1) {
    int v = __shfl_up(incl, off, 64);
    if (lane >= off) incl += v;
  }
  if (lane == 63) wtot[wave] = incl;
  __syncthreads();
  int offtot = 0, Ktot = 0;
  #pragma unroll
  for (int w2 = 0; w2 < 16; ++w2) {
    const int v = wtot[w2];
    if (w2 < wave) offtot += v;
    Ktot += v;
  }
  incl += offtot;
  const int K = Ktot;

  if (t < N_NODES) {
    const int pos = keep ? (incl - 1) : (K + (t - incl));
    idx[b * N_NODES + pos]      = t;
    alpha[b * N_NODES + t]      = a;
    mask_out[b * N_NODES + t]   = (t < K) ? 1.0f : 0.0f;
    if (t == 0) Kbuf[b] = K;
  }
}

// ---------------------------------------------------------------------------
// K2: fused gathers. Blocks [0, XBLOCKS): x-gather (wave per row, float4).
// Blocks [XBLOCKS, XBLOCKS+ABLOCKS): A-gather, 16 rows per block,
// wave per row, float4 writes; cols >= K and rows >= K are zero.
// ---------------------------------------------------------------------------
__global__ __launch_bounds__(256)
void k_gather(const float* __restrict__ x,
              const float* __restrict__ A,
              const float* __restrict__ alpha,
              const int* __restrict__ idx,
              const int* __restrict__ Kbuf,
              float* __restrict__ xo,
              float* __restrict__ Ao) {
  const int bid  = blockIdx.x;
  const int t    = threadIdx.x;
  const int wave = t >> 6;
  const int lane = t & 63;

  if (bid < XBLOCKS) {
    // ---- x part: xo[b,i,:] = x[b, idx[b,i], :] * alpha[b, idx[b,i]] ----
    const int row = bid * 4 + wave;          // b*N + i
    const int b   = row / N_NODES;
    const int src = idx[row];
    const float a = alpha[b * N_NODES + src];
    float4 v = reinterpret_cast<const float4*>(
        x + ((size_t)b * N_NODES + src) * C_DIM)[lane];
    v.x *= a; v.y *= a; v.z *= a; v.w *= a;
    reinterpret_cast<float4*>(xo + (size_t)row * C_DIM)[lane] = v;
  } else {
    // ---- A part ----
    const int abid = bid - XBLOCKS;
    const int b    = abid / ABLK_PER_B;
    const int i0   = (abid % ABLK_PER_B) * A_ROWTILE;

    __shared__ int sidx[N_NODES];
    const int K = Kbuf[b];
    for (int j = t; j < K; j += 256) sidx[j] = idx[b * N_NODES + j];
    __syncthreads();

    const float* Ab  = A  + (size_t)b * N_NODES * N_NODES;
    float*       Aob = Ao + (size_t)b * N_NODES * N_NODES;

    for (int ii = wave; ii < A_ROWTILE; ii += 4) {
      const int i = i0 + ii;
      if (i >= N_NODES) break;
      float4* orow = reinterpret_cast<float4*>(Aob + (size_t)i * N_NODES);
      if (i < K) {
        const float* Arow = Ab + (size_t)sidx[i] * N_NODES;
        for (int j4 = lane; j4 < NV4; j4 += 64) {
          const int j = j4 * 4;
          float4 v;
          v.x = (j + 0 < K) ? Arow[sidx[j + 0]] : 0.0f;
          v.y = (j + 1 < K) ? Arow[sidx[j + 1]] : 0.0f;
          v.z = (j + 2 < K) ? Arow[sidx[j + 2]] : 0.0f;
          v.w = (j + 3 < K) ? Arow[sidx[j + 3]] : 0.0f;
          orow[j4] = v;
        }
      } else {
        const float4 z = {0.0f, 0.0f, 0.0f, 0.0f};
        for (int j4 = lane; j4 < NV4; j4 += 64) orow[j4] = z;
      }
    }
  }
}

// ---------------------------------------------------------------------------
extern "C" void kernel_launch(void* const* d_in, const int* in_sizes, int n_in,
                              void* d_out, int out_size, void* d_ws, size_t ws_size,
                              hipStream_t stream) {
  const float* x    = (const float*)d_in[0];
  const float* A    = (const float*)d_in[1];
  const int*   mask = (const int*)d_in[2];
  const float* W    = (const float*)d_in[3];

  const size_t BN = (size_t)B_DIM * N_NODES;

  float* xo = (float*)d_out;                       // (B,N,C)
  float* Ao = xo + BN * C_DIM;                     // (B,N,N)
  float* mo = Ao + BN * N_NODES;                   // (B,N) as 0.0/1.0

  // workspace layout
  float* alpha = (float*)d_ws;                     // B*N floats
  int*   idx   = (int*)(alpha + BN);               // B*N ints
  int*   Kbuf  = idx + BN;                         // B ints

  k_score_compact<<<B_DIM, 1024, 0, stream>>>(x, W, mask, alpha, idx, Kbuf, mo);
  k_gather<<<XBLOCKS + ABLOCKS, 256, 0, stream>>>(x, A, alpha, idx, Kbuf, xo, Ao);
}

// Round 3
// 43.910 us; speedup vs baseline: 1.4643x; 1.4643x over previous
//
#include <hip/hip_runtime.h>

// Problem constants (B=64, N=600, C=256)
#define B_DIM 64
#define N_NODES 600
#define C_DIM 256
#define NV4 (N_NODES / 4)          // 150 float4 per A row
#define XROWS (B_DIM * N_NODES)    // 38400
#define XBLOCKS (XROWS / 4)        // 9600 (4 rows per 256-thr block)
#define A_ROWTILE 16
#define ABLK_PER_B ((N_NODES + A_ROWTILE - 1) / A_ROWTILE)  // 38
#define ABLOCKS (B_DIM * ABLK_PER_B)                        // 2432

constexpr float kThr = 0.003f;   // THRESHOLD
constexpr float kEps = 1e-7f;    // EPS

// ---------------------------------------------------------------------------
// K1: scores = x . W per (b,n) row -> alpha_pre = exp(score)*mask.
// WIDE: 9600 blocks x 256 thr, one wave per row (this was the R1->R2 lesson:
// the 39 MB x-read needs full-chip parallelism, not 64 blocks).
// ---------------------------------------------------------------------------
__global__ __launch_bounds__(256)
void k_scores(const float* __restrict__ x,
              const float* __restrict__ W,
              const int* __restrict__ mask,
              float* __restrict__ alpha_pre) {
  const int row  = blockIdx.x * 4 + (threadIdx.x >> 6);  // b*N + n
  const int lane = threadIdx.x & 63;
  const float4 xv = reinterpret_cast<const float4*>(x + (size_t)row * C_DIM)[lane];
  const float4 wv = reinterpret_cast<const float4*>(W)[lane];
  float s = xv.x * wv.x + xv.y * wv.y + xv.z * wv.z + xv.w * wv.w;
  #pragma unroll
  for (int off = 32; off > 0; off >>= 1) s += __shfl_down(s, off, 64);
  if (lane == 0) {
    alpha_pre[row] = (mask[row] != 0) ? expf(s) : 0.0f;
  }
}

// ---------------------------------------------------------------------------
// K2: per-batch normalize + threshold + stable compaction (wave scan).
// One block (1024 thr) per batch; touches only ~2.4 KB/block of alpha_pre,
// so 64 blocks is fine here.
// Sum tree identical to the passing R0/R1 version (threshold numerics).
// ---------------------------------------------------------------------------
__global__ __launch_bounds__(1024)
void k_compact(float* __restrict__ alpha,     // in: alpha_pre, out: alpha
               int* __restrict__ idx,
               int* __restrict__ Kbuf,
               float* __restrict__ mask_out) {
  const int b    = blockIdx.x;
  const int t    = threadIdx.x;
  const int wave = t >> 6;
  const int lane = t & 63;

  __shared__ float fs[1024];
  __shared__ int   wtot[16];

  const float ap = (t < N_NODES) ? alpha[b * N_NODES + t] : 0.0f;

  // balanced tree sum (identical order to round-0 passing kernel)
  fs[t] = ap;
  __syncthreads();
  #pragma unroll
  for (int off = 512; off > 0; off >>= 1) {
    if (t < off) fs[t] += fs[t + off];
    __syncthreads();
  }
  const float S = fs[0];

  const float a = ap / (S + kEps);
  // mask==0 => ap==0 => a==0 => not kept, so (a > thr) alone suffices
  const int keep = (t < N_NODES && a > kThr) ? 1 : 0;

  // wave-level inclusive scan of keep
  int incl = keep;
  #pragma unroll
  for (int off = 1; off < 64; off <<= 1) {
    int v = __shfl_up(incl, off, 64);
    if (lane >= off) incl += v;
  }
  if (lane == 63) wtot[wave] = incl;
  __syncthreads();
  int offtot = 0, Ktot = 0;
  #pragma unroll
  for (int w2 = 0; w2 < 16; ++w2) {
    const int v = wtot[w2];
    if (w2 < wave) offtot += v;
    Ktot += v;
  }
  incl += offtot;
  const int K = Ktot;

  if (t < N_NODES) {
    const int pos = keep ? (incl - 1) : (K + (t - incl));
    idx[b * N_NODES + pos]    = t;
    alpha[b * N_NODES + t]    = a;
    mask_out[b * N_NODES + t] = (t < K) ? 1.0f : 0.0f;
    if (t == 0) Kbuf[b] = K;
  }
}

// ---------------------------------------------------------------------------
// K3: fused gathers. Blocks [0, XBLOCKS): x-gather (wave per row, float4).
// Blocks [XBLOCKS, XBLOCKS+ABLOCKS): A-gather, 16 rows per block,
// wave per row, float4 writes; cols >= K and rows >= K are zero.
// ---------------------------------------------------------------------------
__global__ __launch_bounds__(256)
void k_gather(const float* __restrict__ x,
              const float* __restrict__ A,
              const float* __restrict__ alpha,
              const int* __restrict__ idx,
              const int* __restrict__ Kbuf,
              float* __restrict__ xo,
              float* __restrict__ Ao) {
  const int bid  = blockIdx.x;
  const int t    = threadIdx.x;
  const int wave = t >> 6;
  const int lane = t & 63;

  if (bid < XBLOCKS) {
    // ---- x part: xo[b,i,:] = x[b, idx[b,i], :] * alpha[b, idx[b,i]] ----
    const int row = bid * 4 + wave;          // b*N + i
    const int b   = row / N_NODES;
    const int src = idx[row];
    const float a = alpha[b * N_NODES + src];
    float4 v = reinterpret_cast<const float4*>(
        x + ((size_t)b * N_NODES + src) * C_DIM)[lane];
    v.x *= a; v.y *= a; v.z *= a; v.w *= a;
    reinterpret_cast<float4*>(xo + (size_t)row * C_DIM)[lane] = v;
  } else {
    // ---- A part ----
    const int abid = bid - XBLOCKS;
    const int b    = abid / ABLK_PER_B;
    const int i0   = (abid % ABLK_PER_B) * A_ROWTILE;

    __shared__ int sidx[N_NODES];
    const int K = Kbuf[b];
    for (int j = t; j < K; j += 256) sidx[j] = idx[b * N_NODES + j];
    __syncthreads();

    const float* Ab  = A  + (size_t)b * N_NODES * N_NODES;
    float*       Aob = Ao + (size_t)b * N_NODES * N_NODES;

    for (int ii = wave; ii < A_ROWTILE; ii += 4) {
      const int i = i0 + ii;
      if (i >= N_NODES) break;
      float4* orow = reinterpret_cast<float4*>(Aob + (size_t)i * N_NODES);
      if (i < K) {
        const float* Arow = Ab + (size_t)sidx[i] * N_NODES;
        for (int j4 = lane; j4 < NV4; j4 += 64) {
          const int j = j4 * 4;
          float4 v;
          v.x = (j + 0 < K) ? Arow[sidx[j + 0]] : 0.0f;
          v.y = (j + 1 < K) ? Arow[sidx[j + 1]] : 0.0f;
          v.z = (j + 2 < K) ? Arow[sidx[j + 2]] : 0.0f;
          v.w = (j + 3 < K) ? Arow[sidx[j + 3]] : 0.0f;
          orow[j4] = v;
        }
      } else {
        const float4 z = {0.0f, 0.0f, 0.0f, 0.0f};
        for (int j4 = lane; j4 < NV4; j4 += 64) orow[j4] = z;
      }
    }
  }
}

// ---------------------------------------------------------------------------
extern "C" void kernel_launch(void* const* d_in, const int* in_sizes, int n_in,
                              void* d_out, int out_size, void* d_ws, size_t ws_size,
                              hipStream_t stream) {
  const float* x    = (const float*)d_in[0];
  const float* A    = (const float*)d_in[1];
  const int*   mask = (const int*)d_in[2];
  const float* W    = (const float*)d_in[3];

  const size_t BN = (size_t)B_DIM * N_NODES;

  float* xo = (float*)d_out;                       // (B,N,C)
  float* Ao = xo + BN * C_DIM;                     // (B,N,N)
  float* mo = Ao + BN * N_NODES;                   // (B,N) as 0.0/1.0

  // workspace layout
  float* alpha = (float*)d_ws;                     // B*N floats
  int*   idx   = (int*)(alpha + BN);               // B*N ints
  int*   Kbuf  = idx + BN;                         // B ints

  k_scores<<<XBLOCKS, 256, 0, stream>>>(x, W, mask, alpha);
  k_compact<<<B_DIM, 1024, 0, stream>>>(alpha, idx, Kbuf, mo);
  k_gather<<<XBLOCKS + ABLOCKS, 256, 0, stream>>>(x, A, alpha, idx, Kbuf, xo, Ao);
}